// Round 1
// baseline (706.444 us; speedup 1.0000x reference)
//
#include <hip/hip_runtime.h>
#include <hip/hip_bf16.h>

typedef __attribute__((ext_vector_type(8))) short bf16x8;
typedef __attribute__((ext_vector_type(4))) float f32x4;

__device__ __forceinline__ float bf2f(ushort u) {
    union { unsigned u; float f; } x; x.u = ((unsigned)u) << 16; return x.f;
}
__device__ __forceinline__ ushort f2bf(float f) {
    union { float f; unsigned u; } x; x.f = f;
    unsigned r = (x.u + 0x7fffu + ((x.u >> 16) & 1u)) >> 16;
    return (ushort)r;
}
__device__ __forceinline__ void gload_lds16(const ushort* g, ushort* l) {
    __builtin_amdgcn_global_load_lds((const __attribute__((address_space(1))) void*)g,
                                     (__attribute__((address_space(3))) void*)l, 16, 0, 0);
}

// ---------------- prep: x + positional encoding -> bf16 ----------------
__global__ void prep_x(const float* __restrict__ x, ushort* __restrict__ xb) {
    int idx = blockIdx.x * blockDim.x + threadIdx.x;   // 1,048,576 threads
    int d0 = (idx & 127) * 4;
    int row = idx >> 7;                                 // b*4096 + n
    if (row >= 8192) return;
    int n = row & 4095;
    const float4 xv = *(const float4*)(x + (size_t)row * 512 + d0);
    float v[4] = { xv.x, xv.y, xv.z, xv.w };
    ushort4 st;
    ushort o[4];
#pragma unroll
    for (int j = 0; j < 4; ++j) {
        int d = d0 + j;
        float e = (float)(d & ~1) * (1.0f / 512.0f);
        float inv = expf(e * -9.210340371976184f);      // 10000^-e
        float ang = (float)n * inv;
        float pe = (d & 1) ? cosf(ang) : sinf(ang);
        o[j] = f2bf(v[j] + pe);
    }
    st.x = o[0]; st.y = o[1]; st.z = o[2]; st.w = o[3];
    *(ushort4*)(xb + (size_t)row * 512 + d0) = st;
}

// ---------------- weight transpose fp32 [K][N] -> bf16 [N][K] ----------------
__global__ void transpose_w(const float* __restrict__ W, ushort* __restrict__ Wt, int K, int N) {
    int idx = blockIdx.x * 256 + threadIdx.x;
    if (idx >= K * N) return;
    int k = idx / N, n = idx - k * N;
    Wt[(size_t)n * K + k] = f2bf(W[idx]);
}

// ---------------- GEMM: qkv = Xbf[8192][512] @ W[512][1536] (Wt = W^T) ----------------
// scatter epilogue -> Q[B,H,N,64], K[B,H,N,64], V^T[B,H,64,N]  (bf16)
__global__ __launch_bounds__(256) void gemm_qkv(const ushort* __restrict__ X, const ushort* __restrict__ Wt,
                                                ushort* __restrict__ Q, ushort* __restrict__ Kk,
                                                ushort* __restrict__ VT) {
    __shared__ __align__(16) ushort As[128 * 64];
    __shared__ __align__(16) ushort Bs[128 * 64];
    const int tid = threadIdx.x;
    const int lane = tid & 63;
    const int wid = tid >> 6;
    const int m0 = blockIdx.x * 128;
    const int n0 = blockIdx.y * 128;
    const int wm = (wid >> 1) * 64;
    const int wn = (wid & 1) * 64;
    const int g = lane >> 4;
    const int r16 = lane & 15;
    const int srow = tid >> 3;
    const int scol = (tid & 7) * 8;
    f32x4 acc[4][4] = {};
    for (int k0 = 0; k0 < 512; k0 += 64) {
#pragma unroll
        for (int c = 0; c < 4; ++c) {
            int row = srow + c * 32;
            gload_lds16(X  + (size_t)(m0 + row) * 512 + k0 + scol, As + row * 64 + scol);
            gload_lds16(Wt + (size_t)(n0 + row) * 512 + k0 + scol, Bs + row * 64 + scol);
        }
        asm volatile("s_waitcnt vmcnt(0)" ::: "memory");
        __syncthreads();
#pragma unroll
        for (int kk = 0; kk < 2; ++kk) {
            bf16x8 af[4], bfr[4];
#pragma unroll
            for (int t = 0; t < 4; ++t) af[t]  = *(const bf16x8*)(As + (wm + t * 16 + r16) * 64 + kk * 32 + g * 8);
#pragma unroll
            for (int t = 0; t < 4; ++t) bfr[t] = *(const bf16x8*)(Bs + (wn + t * 16 + r16) * 64 + kk * 32 + g * 8);
#pragma unroll
            for (int mt = 0; mt < 4; ++mt)
#pragma unroll
                for (int nt = 0; nt < 4; ++nt)
                    acc[mt][nt] = __builtin_amdgcn_mfma_f32_16x16x32_bf16(af[mt], bfr[nt], acc[mt][nt], 0, 0, 0);
        }
        __syncthreads();
    }
    const int rbase = g * 4;
#pragma unroll
    for (int nt = 0; nt < 4; ++nt) {
        int col = n0 + wn + nt * 16 + r16;   // 0..1535
        int which = col >> 9;                // 0=q 1=k 2=v (uniform per block)
        int d = col & 511;
        int h = d >> 6;
        int hd = d & 63;
#pragma unroll
        for (int mt = 0; mt < 4; ++mt) {
#pragma unroll
            for (int r = 0; r < 4; ++r) {
                int rowm = m0 + wm + mt * 16 + rbase + r;  // b*4096+n
                int b = rowm >> 12, n = rowm & 4095;
                ushort val = f2bf(acc[mt][nt][r]);
                size_t bh = (size_t)b * 8 + h;
                if (which == 0)      Q [(bh * 4096 + n) * 64 + hd] = val;
                else if (which == 1) Kk[(bh * 4096 + n) * 64 + hd] = val;
                else                 VT[(bh * 64 + hd) * 4096 + n] = val;
            }
        }
    }
}

// ---------------- flash attention: 1 block = (b,h) x 64 Q-rows, 4 waves x 16 rows ----------------
__global__ __launch_bounds__(256) void attn(const ushort* __restrict__ Q, const ushort* __restrict__ Kg,
                                            const ushort* __restrict__ VT, ushort* __restrict__ AO) {
    __shared__ __align__(16) ushort P[4][16][72];   // per-wave P tile, padded 64->72
    const int tid = threadIdx.x;
    const int lane = tid & 63;
    const int w = tid >> 6;
    const int g = lane >> 4;
    const int r16 = lane & 15;
    const int bh = blockIdx.y;
    const int b = bh >> 3, h = bh & 7;
    const int q0 = blockIdx.x * 64 + w * 16;
    const size_t base = (size_t)bh * (4096 * 64);

    bf16x8 qf[2];
    {
        const ushort* qp = Q + base + (size_t)(q0 + r16) * 64;
#pragma unroll
        for (int kk = 0; kk < 2; ++kk) {
            bf16x8 t = *(const bf16x8*)(qp + kk * 32 + g * 8);
#pragma unroll
            for (int e = 0; e < 8; ++e) t[e] = (short)f2bf(bf2f((ushort)t[e]) * 0.125f);  // exact
            qf[kk] = t;
        }
    }
    float m_i[4], l_i[4];
    f32x4 accO[4] = {};
#pragma unroll
    for (int r = 0; r < 4; ++r) { m_i[r] = -1e30f; l_i[r] = 0.f; }

    for (int kt = 0; kt < 64; ++kt) {
        const int kb = kt * 64;
        f32x4 s[4] = {};
#pragma unroll
        for (int kk = 0; kk < 2; ++kk) {
#pragma unroll
            for (int ct = 0; ct < 4; ++ct) {
                bf16x8 kf = *(const bf16x8*)(Kg + base + (size_t)(kb + ct * 16 + r16) * 64 + kk * 32 + g * 8);
                s[ct] = __builtin_amdgcn_mfma_f32_16x16x32_bf16(qf[kk], kf, s[ct], 0, 0, 0);
            }
        }
        float mx[4], rs[4], mnew[4], scl[4];
#pragma unroll
        for (int r = 0; r < 4; ++r) mx[r] = fmaxf(fmaxf(s[0][r], s[1][r]), fmaxf(s[2][r], s[3][r]));
#pragma unroll
        for (int m = 1; m <= 8; m <<= 1)
#pragma unroll
            for (int r = 0; r < 4; ++r) mx[r] = fmaxf(mx[r], __shfl_xor(mx[r], m));
#pragma unroll
        for (int r = 0; r < 4; ++r) {
            mnew[r] = fmaxf(m_i[r], mx[r]);
            scl[r] = __expf(m_i[r] - mnew[r]);
            rs[r] = 0.f;
        }
#pragma unroll
        for (int ct = 0; ct < 4; ++ct)
#pragma unroll
            for (int r = 0; r < 4; ++r) {
                float p = __expf(s[ct][r] - mnew[r]);
                s[ct][r] = p;
                rs[r] += p;
            }
#pragma unroll
        for (int m = 1; m <= 8; m <<= 1)
#pragma unroll
            for (int r = 0; r < 4; ++r) rs[r] += __shfl_xor(rs[r], m);
#pragma unroll
        for (int r = 0; r < 4; ++r) { l_i[r] = l_i[r] * scl[r] + rs[r]; m_i[r] = mnew[r]; }
#pragma unroll
        for (int ct = 0; ct < 4; ++ct)
#pragma unroll
            for (int r = 0; r < 4; ++r) accO[ct][r] *= scl[r];
        // P (D-layout) -> LDS, then reread as A-fragment (transpose)
#pragma unroll
        for (int ct = 0; ct < 4; ++ct)
#pragma unroll
            for (int r = 0; r < 4; ++r)
                P[w][g * 4 + r][ct * 16 + r16] = f2bf(s[ct][r]);
        __syncthreads();
#pragma unroll
        for (int kk = 0; kk < 2; ++kk) {
            bf16x8 pa = *(const bf16x8*)(&P[w][r16][kk * 32 + g * 8]);
#pragma unroll
            for (int ct = 0; ct < 4; ++ct) {
                bf16x8 vf = *(const bf16x8*)(VT + base + (size_t)(ct * 16 + r16) * 4096 + kb + kk * 32 + g * 8);
                accO[ct] = __builtin_amdgcn_mfma_f32_16x16x32_bf16(pa, vf, accO[ct], 0, 0, 0);
            }
        }
        __syncthreads();
    }
#pragma unroll
    for (int r = 0; r < 4; ++r) {
        float inv = 1.0f / l_i[r];
        int n = q0 + g * 4 + r;
        ushort* op = AO + ((size_t)(b * 4096 + n)) * 512 + h * 64;
#pragma unroll
        for (int ct = 0; ct < 4; ++ct)
            op[ct * 16 + r16] = f2bf(accO[ct][r] * inv);
    }
}

// ---------------- GEMM: out = AO[8192][512] @ lin_w[512][512] + b  (fp32 out) ----------------
__global__ __launch_bounds__(256) void gemm_out(const ushort* __restrict__ A, const ushort* __restrict__ Wt,
                                                const float* __restrict__ bias, float* __restrict__ out) {
    __shared__ __align__(16) ushort As[128 * 64];
    __shared__ __align__(16) ushort Bs[128 * 64];
    const int tid = threadIdx.x;
    const int lane = tid & 63;
    const int wid = tid >> 6;
    const int m0 = blockIdx.x * 128;
    const int n0 = blockIdx.y * 128;
    const int wm = (wid >> 1) * 64;
    const int wn = (wid & 1) * 64;
    const int g = lane >> 4;
    const int r16 = lane & 15;
    const int srow = tid >> 3;
    const int scol = (tid & 7) * 8;
    f32x4 acc[4][4] = {};
    for (int k0 = 0; k0 < 512; k0 += 64) {
#pragma unroll
        for (int c = 0; c < 4; ++c) {
            int row = srow + c * 32;
            gload_lds16(A  + (size_t)(m0 + row) * 512 + k0 + scol, As + row * 64 + scol);
            gload_lds16(Wt + (size_t)(n0 + row) * 512 + k0 + scol, Bs + row * 64 + scol);
        }
        asm volatile("s_waitcnt vmcnt(0)" ::: "memory");
        __syncthreads();
#pragma unroll
        for (int kk = 0; kk < 2; ++kk) {
            bf16x8 af[4], bfr[4];
#pragma unroll
            for (int t = 0; t < 4; ++t) af[t]  = *(const bf16x8*)(As + (wm + t * 16 + r16) * 64 + kk * 32 + g * 8);
#pragma unroll
            for (int t = 0; t < 4; ++t) bfr[t] = *(const bf16x8*)(Bs + (wn + t * 16 + r16) * 64 + kk * 32 + g * 8);
#pragma unroll
            for (int mt = 0; mt < 4; ++mt)
#pragma unroll
                for (int nt = 0; nt < 4; ++nt)
                    acc[mt][nt] = __builtin_amdgcn_mfma_f32_16x16x32_bf16(af[mt], bfr[nt], acc[mt][nt], 0, 0, 0);
        }
        __syncthreads();
    }
    const int rbase = g * 4;
#pragma unroll
    for (int nt = 0; nt < 4; ++nt) {
        int col = n0 + wn + nt * 16 + r16;
        float bv = bias[col];
#pragma unroll
        for (int mt = 0; mt < 4; ++mt) {
#pragma unroll
            for (int r = 0; r < 4; ++r) {
                int rowm = m0 + wm + mt * 16 + rbase + r;
                out[(size_t)rowm * 512 + col] = acc[mt][nt][r] + bv;
            }
        }
    }
}

extern "C" void kernel_launch(void* const* d_in, const int* in_sizes, int n_in,
                              void* d_out, int out_size, void* d_ws, size_t ws_size,
                              hipStream_t stream) {
    const float* x     = (const float*)d_in[0];
    const float* qkv_w = (const float*)d_in[1];
    const float* lin_w = (const float*)d_in[2];
    const float* lin_b = (const float*)d_in[3];
    float* out = (float*)d_out;
    char* ws = (char*)d_ws;
    // workspace layout (bytes)
    ushort* xb    = (ushort*)(ws + 0);                       // 8192*512*2  = 8,388,608
    ushort* qkvwt = (ushort*)(ws + 8388608);                 // 1536*512*2  = 1,572,864
    ushort* linwt = (ushort*)(ws + 8388608 + 1572864);       // 512*512*2   =   524,288
    ushort* Qb    = (ushort*)(ws + 10485760);                // 8 MB
    ushort* Kb    = (ushort*)(ws + 10485760 + 8388608);      // 8 MB
    ushort* VTb   = (ushort*)(ws + 10485760 + 16777216);     // 8 MB
    ushort* AOb   = (ushort*)(ws + 10485760 + 25165824);     // 8 MB  (end = 44,040,192)

    prep_x<<<4096, 256, 0, stream>>>(x, xb);
    transpose_w<<<3072, 256, 0, stream>>>(qkv_w, qkvwt, 512, 1536);
    transpose_w<<<1024, 256, 0, stream>>>(lin_w, linwt, 512, 512);
    gemm_qkv<<<dim3(64, 12), 256, 0, stream>>>(xb, qkvwt, Qb, Kb, VTb);
    attn<<<dim3(64, 16), 256, 0, stream>>>(Qb, Kb, VTb, AOb);
    gemm_out<<<dim3(64, 4), 256, 0, stream>>>(AOb, linwt, lin_b, out);
}

// Round 2
// 360.153 us; speedup vs baseline: 1.9615x; 1.9615x over previous
//
#include <hip/hip_runtime.h>
#include <hip/hip_bf16.h>

typedef __attribute__((ext_vector_type(8))) short bf16x8;
typedef __attribute__((ext_vector_type(4))) float f32x4;
typedef __attribute__((ext_vector_type(16))) float f32x16;
typedef __attribute__((ext_vector_type(4))) int i32x4;

__device__ __forceinline__ float bf2f(ushort u) {
    union { unsigned u; float f; } x; x.u = ((unsigned)u) << 16; return x.f;
}
__device__ __forceinline__ ushort f2bf(float f) {
    union { float f; unsigned u; } x; x.f = f;
    unsigned r = (x.u + 0x7fffu + ((x.u >> 16) & 1u)) >> 16;
    return (ushort)r;
}
__device__ __forceinline__ unsigned cvtpk(float lo, float hi) {
    unsigned r;
    asm("v_cvt_pk_bf16_f32 %0, %1, %2" : "=v"(r) : "v"(lo), "v"(hi));
    return r;
}
__device__ __forceinline__ f32x16 zero16() {
    f32x16 z;
#pragma unroll
    for (int i = 0; i < 16; ++i) z[i] = 0.f;
    return z;
}
__device__ __forceinline__ void gload_lds16(const ushort* g, ushort* l) {
    __builtin_amdgcn_global_load_lds((const __attribute__((address_space(1))) void*)g,
                                     (__attribute__((address_space(3))) void*)l, 16, 0, 0);
}

// ---------------- prep: x + positional encoding -> bf16 ----------------
__global__ void prep_x(const float* __restrict__ x, ushort* __restrict__ xb) {
    int idx = blockIdx.x * blockDim.x + threadIdx.x;
    int d0 = (idx & 127) * 4;
    int row = idx >> 7;                                 // b*4096 + n
    if (row >= 8192) return;
    int n = row & 4095;
    const float4 xv = *(const float4*)(x + (size_t)row * 512 + d0);
    float v[4] = { xv.x, xv.y, xv.z, xv.w };
    ushort4 st;
    ushort o[4];
#pragma unroll
    for (int j = 0; j < 4; ++j) {
        int d = d0 + j;
        float e = (float)(d & ~1) * (1.0f / 512.0f);
        float inv = expf(e * -9.210340371976184f);      // 10000^-e
        float ang = (float)n * inv;
        float pe = (d & 1) ? cosf(ang) : sinf(ang);
        o[j] = f2bf(v[j] + pe);
    }
    st.x = o[0]; st.y = o[1]; st.z = o[2]; st.w = o[3];
    *(ushort4*)(xb + (size_t)row * 512 + d0) = st;
}

// ---------------- weight transpose fp32 [K][N] -> bf16 [N][K] ----------------
__global__ void transpose_w(const float* __restrict__ W, ushort* __restrict__ Wt, int K, int N) {
    int idx = blockIdx.x * 256 + threadIdx.x;
    if (idx >= K * N) return;
    int k = idx / N, n = idx - k * N;
    Wt[(size_t)n * K + k] = f2bf(W[idx]);
}

// ---------------- GEMM: qkv = Xbf[8192][512] @ W[512][1536] (Wt = W^T) ----------------
__global__ __launch_bounds__(256) void gemm_qkv(const ushort* __restrict__ X, const ushort* __restrict__ Wt,
                                                ushort* __restrict__ Q, ushort* __restrict__ Kk,
                                                ushort* __restrict__ VT) {
    __shared__ __align__(16) ushort As[128 * 64];
    __shared__ __align__(16) ushort Bs[128 * 64];
    const int tid = threadIdx.x;
    const int lane = tid & 63;
    const int wid = tid >> 6;
    const int m0 = blockIdx.x * 128;
    const int n0 = blockIdx.y * 128;
    const int wm = (wid >> 1) * 64;
    const int wn = (wid & 1) * 64;
    const int g = lane >> 4;
    const int r16 = lane & 15;
    const int srow = tid >> 3;
    const int scol = (tid & 7) * 8;
    f32x4 acc[4][4] = {};
    for (int k0 = 0; k0 < 512; k0 += 64) {
#pragma unroll
        for (int c = 0; c < 4; ++c) {
            int row = srow + c * 32;
            gload_lds16(X  + (size_t)(m0 + row) * 512 + k0 + scol, As + row * 64 + scol);
            gload_lds16(Wt + (size_t)(n0 + row) * 512 + k0 + scol, Bs + row * 64 + scol);
        }
        asm volatile("s_waitcnt vmcnt(0)" ::: "memory");
        __syncthreads();
#pragma unroll
        for (int kk = 0; kk < 2; ++kk) {
            bf16x8 af[4], bfr[4];
#pragma unroll
            for (int t = 0; t < 4; ++t) af[t]  = *(const bf16x8*)(As + (wm + t * 16 + r16) * 64 + kk * 32 + g * 8);
#pragma unroll
            for (int t = 0; t < 4; ++t) bfr[t] = *(const bf16x8*)(Bs + (wn + t * 16 + r16) * 64 + kk * 32 + g * 8);
#pragma unroll
            for (int mt = 0; mt < 4; ++mt)
#pragma unroll
                for (int nt = 0; nt < 4; ++nt)
                    acc[mt][nt] = __builtin_amdgcn_mfma_f32_16x16x32_bf16(af[mt], bfr[nt], acc[mt][nt], 0, 0, 0);
        }
        __syncthreads();
    }
    const int rbase = g * 4;
#pragma unroll
    for (int nt = 0; nt < 4; ++nt) {
        int col = n0 + wn + nt * 16 + r16;   // 0..1535
        int which = col >> 9;                // 0=q 1=k 2=v (uniform per block)
        int d = col & 511;
        int h = d >> 6;
        int hd = d & 63;
#pragma unroll
        for (int mt = 0; mt < 4; ++mt) {
#pragma unroll
            for (int r = 0; r < 4; ++r) {
                int rowm = m0 + wm + mt * 16 + rbase + r;  // b*4096+n
                int b = rowm >> 12, n = rowm & 4095;
                ushort val = f2bf(acc[mt][nt][r]);
                size_t bh = (size_t)b * 8 + h;
                if (which == 0)      Q [(bh * 4096 + n) * 64 + hd] = val;
                else if (which == 1) Kk[(bh * 4096 + n) * 64 + hd] = val;
                else                 VT[(bh * 64 + hd) * 4096 + n] = val;
            }
        }
    }
}

// ---------------- flash attention, swapped-QK^T, no LDS, no barriers ----------------
// 1 wave = 32 q-rows. Block = 4 independent waves. Grid (32, B*H).
// S^T = mfma(K, Q): lane = one q-row (col=l&31), regs = k-rows (crow(r,hi)).
// Softmax lane-local; P repacked in-register (cvt_pk + shfl_xor(32)) into PV A-frags.
__global__ __launch_bounds__(256) void attn(const ushort* __restrict__ Q, const ushort* __restrict__ Kg,
                                            const ushort* __restrict__ VT, ushort* __restrict__ AO) {
    const int tid = threadIdx.x;
    const int lane = tid & 63;
    const int wid = tid >> 6;
    const int l31 = lane & 31;
    const int hi  = lane >> 5;
    const int bh = blockIdx.y;
    const int b = bh >> 3, h = bh & 7;
    const int q0 = blockIdx.x * 128 + wid * 32;
    const size_t base = (size_t)bh * (4096 * 64);

    // Q B-fragments: qf[ks] lane l elem e = Q[q0+l31][ks*16+hi*8+e] * (0.125*log2e)
    const float qscale = 0.125f * 1.44269504088896f;   // exp2-domain softmax
    bf16x8 qf[4];
    {
        const ushort* qp = Q + base + (size_t)(q0 + l31) * 64 + hi * 8;
#pragma unroll
        for (int ks = 0; ks < 4; ++ks) {
            bf16x8 t = *(const bf16x8*)(qp + ks * 16);
#pragma unroll
            for (int e = 0; e < 8; ++e) t[e] = (short)f2bf(bf2f((ushort)t[e]) * qscale);
            qf[ks] = t;
        }
    }
    f32x16 o0 = zero16(), o1 = zero16();
    float m_i = -1e30f, l_i = 0.f;

    const ushort* kbase = Kg + base + (size_t)l31 * 64 + hi * 8;
    const ushort* vb0 = VT + base + (size_t)l31 * 4096 + hi * 8;          // d-block 0
    const ushort* vb1 = VT + base + (size_t)(l31 + 32) * 4096 + hi * 8;   // d-block 1

    for (int kt = 0; kt < 64; ++kt) {
        const int kb = kt * 64;
        // ---- QK^T: A = K rows (kb..kb+63 in two 32-blocks), B = Q^T
        bf16x8 kf[8];
#pragma unroll
        for (int ks = 0; ks < 4; ++ks) {
            kf[ks]     = *(const bf16x8*)(kbase + (size_t)kb * 64 + ks * 16);
            kf[ks + 4] = *(const bf16x8*)(kbase + (size_t)(kb + 32) * 64 + ks * 16);
        }
        f32x16 s0 = zero16(), s1 = zero16();
#pragma unroll
        for (int ks = 0; ks < 4; ++ks) {
            s0 = __builtin_amdgcn_mfma_f32_32x32x16_bf16(kf[ks],     qf[ks], s0, 0, 0, 0);
            s1 = __builtin_amdgcn_mfma_f32_32x32x16_bf16(kf[ks + 4], qf[ks], s1, 0, 0, 0);
        }
        // ---- V prefetch (latency hides under softmax VALU)
        bf16x8 vf0[4], vf1[4];
#pragma unroll
        for (int ks = 0; ks < 4; ++ks) {
            vf0[ks] = *(const bf16x8*)(vb0 + kb + ks * 16);
            vf1[ks] = *(const bf16x8*)(vb1 + kb + ks * 16);
        }
        // ---- online softmax (exp2 domain), lane-local over 32 regs + partner half
        float mx = s0[0];
#pragma unroll
        for (int r = 1; r < 16; ++r) mx = fmaxf(mx, s0[r]);
#pragma unroll
        for (int r = 0; r < 16; ++r) mx = fmaxf(mx, s1[r]);
        mx = fmaxf(mx, __shfl_xor(mx, 32));
        if (!__all(mx - m_i <= 11.0f)) {                 // defer-max: P bounded by 2^11
            float mnew = fmaxf(m_i, mx);
            float scl = __builtin_exp2f(m_i - mnew);
            l_i *= scl;
            m_i = mnew;
            float so[16];
#pragma unroll
            for (int r = 0; r < 16; ++r) so[r] = __shfl(scl, (r & 3) + 8 * (r >> 2) + 4 * hi);
#pragma unroll
            for (int r = 0; r < 16; ++r) { o0[r] *= so[r]; o1[r] *= so[r]; }
        }
        float rs = 0.f;
#pragma unroll
        for (int r = 0; r < 16; ++r) { s0[r] = __builtin_exp2f(s0[r] - m_i); rs += s0[r]; }
#pragma unroll
        for (int r = 0; r < 16; ++r) { s1[r] = __builtin_exp2f(s1[r] - m_i); rs += s1[r]; }
        rs += __shfl_xor(rs, 32);
        l_i += rs;
        // ---- pack P -> A-fragments (T12) and PV
#pragma unroll
        for (int ks = 0; ks < 4; ++ks) {
            f32x16 p = (ks < 2) ? s0 : s1;               // compile-time select
            const int rA = 8 * (ks & 1), rB = rA + 4;
            unsigned a0 = cvtpk(p[rA],     p[rA + 1]);
            unsigned a1 = cvtpk(p[rA + 2], p[rA + 3]);
            unsigned b0 = cvtpk(p[rB],     p[rB + 1]);
            unsigned b1 = cvtpk(p[rB + 2], p[rB + 3]);
            int send0 = hi ? (int)a0 : (int)b0;
            int send1 = hi ? (int)a1 : (int)b1;
            int rec0 = __shfl_xor(send0, 32);
            int rec1 = __shfl_xor(send1, 32);
            union { i32x4 i; bf16x8 v; } pa;
            pa.i[0] = hi ? rec0 : (int)a0;
            pa.i[1] = hi ? rec1 : (int)a1;
            pa.i[2] = hi ? (int)b0 : rec0;
            pa.i[3] = hi ? (int)b1 : rec1;
            o0 = __builtin_amdgcn_mfma_f32_32x32x16_bf16(pa.v, vf0[ks], o0, 0, 0, 0);
            o1 = __builtin_amdgcn_mfma_f32_32x32x16_bf16(pa.v, vf1[ks], o1, 0, 0, 0);
        }
    }
    // ---- epilogue: O[q][d] / l[q]
    float linv = 1.0f / l_i;
#pragma unroll
    for (int r = 0; r < 16; ++r) {
        int q = (r & 3) + 8 * (r >> 2) + 4 * hi;
        float so = __shfl(linv, q);
        int n = q0 + q;
        ushort* op = AO + ((size_t)(b * 4096 + n)) * 512 + h * 64 + l31;
        op[0]  = f2bf(o0[r] * so);
        op[32] = f2bf(o1[r] * so);
    }
}

// ---------------- GEMM: out = AO[8192][512] @ lin_w[512][512] + b  (fp32 out) ----------------
__global__ __launch_bounds__(256) void gemm_out(const ushort* __restrict__ A, const ushort* __restrict__ Wt,
                                                const float* __restrict__ bias, float* __restrict__ out) {
    __shared__ __align__(16) ushort As[128 * 64];
    __shared__ __align__(16) ushort Bs[128 * 64];
    const int tid = threadIdx.x;
    const int lane = tid & 63;
    const int wid = tid >> 6;
    const int m0 = blockIdx.x * 128;
    const int n0 = blockIdx.y * 128;
    const int wm = (wid >> 1) * 64;
    const int wn = (wid & 1) * 64;
    const int g = lane >> 4;
    const int r16 = lane & 15;
    const int srow = tid >> 3;
    const int scol = (tid & 7) * 8;
    f32x4 acc[4][4] = {};
    for (int k0 = 0; k0 < 512; k0 += 64) {
#pragma unroll
        for (int c = 0; c < 4; ++c) {
            int row = srow + c * 32;
            gload_lds16(A  + (size_t)(m0 + row) * 512 + k0 + scol, As + row * 64 + scol);
            gload_lds16(Wt + (size_t)(n0 + row) * 512 + k0 + scol, Bs + row * 64 + scol);
        }
        asm volatile("s_waitcnt vmcnt(0)" ::: "memory");
        __syncthreads();
#pragma unroll
        for (int kk = 0; kk < 2; ++kk) {
            bf16x8 af[4], bfr[4];
#pragma unroll
            for (int t = 0; t < 4; ++t) af[t]  = *(const bf16x8*)(As + (wm + t * 16 + r16) * 64 + kk * 32 + g * 8);
#pragma unroll
            for (int t = 0; t < 4; ++t) bfr[t] = *(const bf16x8*)(Bs + (wn + t * 16 + r16) * 64 + kk * 32 + g * 8);
#pragma unroll
            for (int mt = 0; mt < 4; ++mt)
#pragma unroll
                for (int nt = 0; nt < 4; ++nt)
                    acc[mt][nt] = __builtin_amdgcn_mfma_f32_16x16x32_bf16(af[mt], bfr[nt], acc[mt][nt], 0, 0, 0);
        }
        __syncthreads();
    }
    const int rbase = g * 4;
#pragma unroll
    for (int nt = 0; nt < 4; ++nt) {
        int col = n0 + wn + nt * 16 + r16;
        float bv = bias[col];
#pragma unroll
        for (int mt = 0; mt < 4; ++mt) {
#pragma unroll
            for (int r = 0; r < 4; ++r) {
                int rowm = m0 + wm + mt * 16 + rbase + r;
                out[(size_t)rowm * 512 + col] = acc[mt][nt][r] + bv;
            }
        }
    }
}

extern "C" void kernel_launch(void* const* d_in, const int* in_sizes, int n_in,
                              void* d_out, int out_size, void* d_ws, size_t ws_size,
                              hipStream_t stream) {
    const float* x     = (const float*)d_in[0];
    const float* qkv_w = (const float*)d_in[1];
    const float* lin_w = (const float*)d_in[2];
    const float* lin_b = (const float*)d_in[3];
    float* out = (float*)d_out;
    char* ws = (char*)d_ws;
    ushort* xb    = (ushort*)(ws + 0);                       // 8 MB
    ushort* qkvwt = (ushort*)(ws + 8388608);                 // 1.5 MB
    ushort* linwt = (ushort*)(ws + 8388608 + 1572864);       // 0.5 MB
    ushort* Qb    = (ushort*)(ws + 10485760);                // 8 MB
    ushort* Kb    = (ushort*)(ws + 10485760 + 8388608);      // 8 MB
    ushort* VTb   = (ushort*)(ws + 10485760 + 16777216);     // 8 MB
    ushort* AOb   = (ushort*)(ws + 10485760 + 25165824);     // 8 MB (end = 44,040,192)

    prep_x<<<4096, 256, 0, stream>>>(x, xb);
    transpose_w<<<3072, 256, 0, stream>>>(qkv_w, qkvwt, 512, 1536);
    transpose_w<<<1024, 256, 0, stream>>>(lin_w, linwt, 512, 512);
    gemm_qkv<<<dim3(64, 12), 256, 0, stream>>>(xb, qkvwt, Qb, Kb, VTb);
    attn<<<dim3(32, 16), 256, 0, stream>>>(Qb, Kb, VTb, AOb);
    gemm_out<<<dim3(64, 4), 256, 0, stream>>>(AOb, linwt, lin_b, out);
}

// Round 7
// 357.642 us; speedup vs baseline: 1.9753x; 1.0070x over previous
//
#include <hip/hip_runtime.h>
#include <hip/hip_bf16.h>

typedef __attribute__((ext_vector_type(8))) short bf16x8;
typedef __attribute__((ext_vector_type(4))) float f32x4;
typedef __attribute__((ext_vector_type(8))) float f32x8;
typedef __attribute__((ext_vector_type(16))) float f32x16;
typedef __attribute__((ext_vector_type(4))) int i32x4;
typedef __attribute__((ext_vector_type(2))) int i32x2;

__device__ __forceinline__ float bf2f(ushort u) {
    union { unsigned u; float f; } x; x.u = ((unsigned)u) << 16; return x.f;
}
__device__ __forceinline__ ushort f2bf(float f) {
    union { float f; unsigned u; } x; x.f = f;
    unsigned r = (x.u + 0x7fffu + ((x.u >> 16) & 1u)) >> 16;
    return (ushort)r;
}
__device__ __forceinline__ unsigned cvtpk(float lo, float hi) {
    unsigned r;
    asm("v_cvt_pk_bf16_f32 %0, %1, %2" : "=v"(r) : "v"(lo), "v"(hi));
    return r;
}
// permlane32_swap via builtin (inline-asm version miscompiled when both
// operands coalesced to one register): returns {[a.lo|b.lo], [a.hi|b.hi]}
// over lane-halves (lo = lanes 0-31, hi = lanes 32-63).
__device__ __forceinline__ void plswap(unsigned &a, unsigned &b) {
    i32x2 r = __builtin_amdgcn_permlane32_swap((int)a, (int)b, false, false);
    a = (unsigned)r[0]; b = (unsigned)r[1];
}
__device__ __forceinline__ float xhalf_max(float x) {
    unsigned a = __float_as_uint(x), b = __float_as_uint(x);
    plswap(a, b);
    return fmaxf(__uint_as_float(a), __uint_as_float(b));
}
__device__ __forceinline__ float xhalf_add(float x) {
    unsigned a = __float_as_uint(x), b = __float_as_uint(x);
    plswap(a, b);
    return __uint_as_float(a) + __uint_as_float(b);
}
__device__ __forceinline__ f32x16 zero16() {
    f32x16 z;
#pragma unroll
    for (int i = 0; i < 16; ++i) z[i] = 0.f;
    return z;
}
__device__ __forceinline__ void gload_lds16(const ushort* g, ushort* l) {
    __builtin_amdgcn_global_load_lds((const __attribute__((address_space(1))) void*)g,
                                     (__attribute__((address_space(3))) void*)l, 16, 0, 0);
}

// ---------------- prep: x + positional encoding -> bf16 ----------------
__global__ void prep_x(const float* __restrict__ x, ushort* __restrict__ xb) {
    int idx = blockIdx.x * blockDim.x + threadIdx.x;
    int d0 = (idx & 127) * 4;
    int row = idx >> 7;                                 // b*4096 + n
    if (row >= 8192) return;
    int n = row & 4095;
    const float4 xv = *(const float4*)(x + (size_t)row * 512 + d0);
    float v[4] = { xv.x, xv.y, xv.z, xv.w };
    ushort4 st;
    ushort o[4];
#pragma unroll
    for (int j = 0; j < 4; ++j) {
        int d = d0 + j;
        float e = (float)(d & ~1) * (1.0f / 512.0f);
        float inv = expf(e * -9.210340371976184f);      // 10000^-e
        float ang = (float)n * inv;
        float pe = (d & 1) ? cosf(ang) : sinf(ang);
        o[j] = f2bf(v[j] + pe);
    }
    st.x = o[0]; st.y = o[1]; st.z = o[2]; st.w = o[3];
    *(ushort4*)(xb + (size_t)row * 512 + d0) = st;
}

// ---------------- tiled weight transpose fp32 [K][N] -> bf16 [N][K] ----------------
__global__ __launch_bounds__(256) void transpose_w(const float* __restrict__ W, ushort* __restrict__ Wt,
                                                   int K, int N) {
    __shared__ float T[64][65];
    const int k0 = blockIdx.x * 64, n0 = blockIdx.y * 64;
    const int tr = threadIdx.x >> 4;           // 0..15
    const int tc = (threadIdx.x & 15) * 4;     // 0,4,...,60
#pragma unroll
    for (int i = 0; i < 4; ++i) {
        int r = tr + i * 16;
        float4 v = *(const float4*)(W + (size_t)(k0 + r) * N + n0 + tc);
        T[r][tc] = v.x; T[r][tc + 1] = v.y; T[r][tc + 2] = v.z; T[r][tc + 3] = v.w;
    }
    __syncthreads();
#pragma unroll
    for (int i = 0; i < 4; ++i) {
        int r = tr + i * 16;                   // n-offset
        ushort4 s;
        s.x = f2bf(T[tc + 0][r]); s.y = f2bf(T[tc + 1][r]);
        s.z = f2bf(T[tc + 2][r]); s.w = f2bf(T[tc + 3][r]);
        *(ushort4*)(Wt + (size_t)(n0 + r) * K + k0 + tc) = s;
    }
}

// ---------------- GEMM: qkv = Xbf[8192][512] @ W[512][1536] (Wt = W^T) ----------------
__global__ __launch_bounds__(256) void gemm_qkv(const ushort* __restrict__ X, const ushort* __restrict__ Wt,
                                                ushort* __restrict__ Q, ushort* __restrict__ Kk,
                                                ushort* __restrict__ VT) {
    __shared__ __align__(16) ushort As[128 * 64];
    __shared__ __align__(16) ushort Bs[128 * 64];
    const int tid = threadIdx.x;
    const int lane = tid & 63;
    const int wid = tid >> 6;
    const int m0 = blockIdx.x * 128;
    const int n0 = blockIdx.y * 128;
    const int wm = (wid >> 1) * 64;
    const int wn = (wid & 1) * 64;
    const int g = lane >> 4;
    const int r16 = lane & 15;
    const int srow = tid >> 3;
    const int scol = (tid & 7) * 8;
    f32x4 acc[4][4] = {};
    for (int k0 = 0; k0 < 512; k0 += 64) {
#pragma unroll
        for (int c = 0; c < 4; ++c) {
            int row = srow + c * 32;
            gload_lds16(X  + (size_t)(m0 + row) * 512 + k0 + scol, As + row * 64 + scol);
            gload_lds16(Wt + (size_t)(n0 + row) * 512 + k0 + scol, Bs + row * 64 + scol);
        }
        asm volatile("s_waitcnt vmcnt(0)" ::: "memory");
        __syncthreads();
#pragma unroll
        for (int kk = 0; kk < 2; ++kk) {
            bf16x8 af[4], bfr[4];
#pragma unroll
            for (int t = 0; t < 4; ++t) af[t]  = *(const bf16x8*)(As + (wm + t * 16 + r16) * 64 + kk * 32 + g * 8);
#pragma unroll
            for (int t = 0; t < 4; ++t) bfr[t] = *(const bf16x8*)(Bs + (wn + t * 16 + r16) * 64 + kk * 32 + g * 8);
#pragma unroll
            for (int mt = 0; mt < 4; ++mt)
#pragma unroll
                for (int nt = 0; nt < 4; ++nt)
                    acc[mt][nt] = __builtin_amdgcn_mfma_f32_16x16x32_bf16(af[mt], bfr[nt], acc[mt][nt], 0, 0, 0);
        }
        __syncthreads();
    }
    const int rbase = g * 4;
#pragma unroll
    for (int nt = 0; nt < 4; ++nt) {
        int col = n0 + wn + nt * 16 + r16;   // 0..1535
        int which = col >> 9;                // 0=q 1=k 2=v (uniform per block)
        int d = col & 511;
        int h = d >> 6;
        int hd = d & 63;
#pragma unroll
        for (int mt = 0; mt < 4; ++mt) {
#pragma unroll
            for (int r = 0; r < 4; ++r) {
                int rowm = m0 + wm + mt * 16 + rbase + r;  // b*4096+n
                int b = rowm >> 12, n = rowm & 4095;
                ushort val = f2bf(acc[mt][nt][r]);
                size_t bh = (size_t)b * 8 + h;
                if (which == 0)      Q [(bh * 4096 + n) * 64 + hd] = val;
                else if (which == 1) Kk[(bh * 4096 + n) * 64 + hd] = val;
                else                 VT[(bh * 64 + hd) * 4096 + n] = val;
            }
        }
    }
}

// ---------------- flash attention step (K reg-double-buffered, permlane softmax) ----------------
__device__ __forceinline__ void attn_step(
    const ushort* __restrict__ kbase, const ushort* __restrict__ vb0, const ushort* __restrict__ vb1,
    const bf16x8 (&qf)[4], bf16x8 (&KC)[8], bf16x8 (&KN)[8],
    f32x16 &o0, f32x16 &o1, float &m_i, float &l_i, int kt)
{
    const int hi = (threadIdx.x >> 5) & 1;
    const int kb = kt * 64;
    const int kbn = (kt < 63 ? kt + 1 : kt) * 64;
    // ---- prefetch next K tile into KN (consumed next step)
#pragma unroll
    for (int ks = 0; ks < 4; ++ks) {
        KN[ks]     = *(const bf16x8*)(kbase + (size_t)kbn * 64 + ks * 16);
        KN[ks + 4] = *(const bf16x8*)(kbase + (size_t)(kbn + 32) * 64 + ks * 16);
    }
    // ---- V for current tile (consumed after softmax; latency hidden)
    bf16x8 vf0[4], vf1[4];
#pragma unroll
    for (int ks = 0; ks < 4; ++ks) {
        vf0[ks] = *(const bf16x8*)(vb0 + kb + ks * 16);
        vf1[ks] = *(const bf16x8*)(vb1 + kb + ks * 16);
    }
    // ---- QK^T on resident KC
    f32x16 s0 = zero16(), s1 = zero16();
    __builtin_amdgcn_s_setprio(1);
#pragma unroll
    for (int ks = 0; ks < 4; ++ks) {
        s0 = __builtin_amdgcn_mfma_f32_32x32x16_bf16(KC[ks],     qf[ks], s0, 0, 0, 0);
        s1 = __builtin_amdgcn_mfma_f32_32x32x16_bf16(KC[ks + 4], qf[ks], s1, 0, 0, 0);
    }
    __builtin_amdgcn_s_setprio(0);
    // ---- row max: max3-fused tree + permlane cross-half
    float q0 = fmaxf(fmaxf(s0[0], s0[1]),  fmaxf(s0[2], s0[3]));
    float q1 = fmaxf(fmaxf(s0[4], s0[5]),  fmaxf(s0[6], s0[7]));
    float q2 = fmaxf(fmaxf(s0[8], s0[9]),  fmaxf(s0[10], s0[11]));
    float q3 = fmaxf(fmaxf(s0[12], s0[13]), fmaxf(s0[14], s0[15]));
    float q4 = fmaxf(fmaxf(s1[0], s1[1]),  fmaxf(s1[2], s1[3]));
    float q5 = fmaxf(fmaxf(s1[4], s1[5]),  fmaxf(s1[6], s1[7]));
    float q6 = fmaxf(fmaxf(s1[8], s1[9]),  fmaxf(s1[10], s1[11]));
    float q7 = fmaxf(fmaxf(s1[12], s1[13]), fmaxf(s1[14], s1[15]));
    float mx = fmaxf(fmaxf(fmaxf(q0, q1), fmaxf(q2, q3)), fmaxf(fmaxf(q4, q5), fmaxf(q6, q7)));
    mx = xhalf_max(mx);
    if (!__all(mx - m_i <= 11.0f)) {                 // defer-max: P bounded by 2^11
        float mnew = fmaxf(m_i, mx);
        float scl = __builtin_exp2f(m_i - mnew);
        l_i *= scl;
        m_i = mnew;
        float so[16];
#pragma unroll
        for (int r = 0; r < 16; ++r) so[r] = __shfl(scl, (r & 3) + 8 * (r >> 2) + 4 * hi);
#pragma unroll
        for (int r = 0; r < 16; ++r) { o0[r] *= so[r]; o1[r] *= so[r]; }
    }
    // ---- p = exp2(s - m)  (pk-sub + 32 exp)
    f32x16 mv;
#pragma unroll
    for (int r = 0; r < 16; ++r) mv[r] = m_i;
    s0 = s0 - mv;
    s1 = s1 - mv;
#pragma unroll
    for (int r = 0; r < 16; ++r) { s0[r] = __builtin_exp2f(s0[r]); s1[r] = __builtin_exp2f(s1[r]); }
    // ---- row sum: pk-add tree + permlane cross-half
    {
        f32x16 t = s0 + s1;
        f32x8 u = __builtin_shufflevector(t, t, 0, 1, 2, 3, 4, 5, 6, 7)
                + __builtin_shufflevector(t, t, 8, 9, 10, 11, 12, 13, 14, 15);
        f32x4 v4 = __builtin_shufflevector(u, u, 0, 1, 2, 3)
                 + __builtin_shufflevector(u, u, 4, 5, 6, 7);
        float rs = (v4[0] + v4[1]) + (v4[2] + v4[3]);
        l_i += xhalf_add(rs);
    }
    // ---- pack P (cvt_pk + permlane32_swap) and PV
    {
        unsigned c0 = cvtpk(s0[0], s0[1]),  c1 = cvtpk(s0[2], s0[3]);
        unsigned d0 = cvtpk(s0[4], s0[5]),  d1 = cvtpk(s0[6], s0[7]);
        plswap(c0, d0); plswap(c1, d1);
        union { i32x4 i; bf16x8 v; } pa;
        pa.i[0] = (int)c0; pa.i[1] = (int)c1; pa.i[2] = (int)d0; pa.i[3] = (int)d1;
        __builtin_amdgcn_s_setprio(1);
        o0 = __builtin_amdgcn_mfma_f32_32x32x16_bf16(pa.v, vf0[0], o0, 0, 0, 0);
        o1 = __builtin_amdgcn_mfma_f32_32x32x16_bf16(pa.v, vf1[0], o1, 0, 0, 0);
        __builtin_amdgcn_s_setprio(0);
    }
    {
        unsigned c0 = cvtpk(s0[8], s0[9]),   c1 = cvtpk(s0[10], s0[11]);
        unsigned d0 = cvtpk(s0[12], s0[13]), d1 = cvtpk(s0[14], s0[15]);
        plswap(c0, d0); plswap(c1, d1);
        union { i32x4 i; bf16x8 v; } pa;
        pa.i[0] = (int)c0; pa.i[1] = (int)c1; pa.i[2] = (int)d0; pa.i[3] = (int)d1;
        __builtin_amdgcn_s_setprio(1);
        o0 = __builtin_amdgcn_mfma_f32_32x32x16_bf16(pa.v, vf0[1], o0, 0, 0, 0);
        o1 = __builtin_amdgcn_mfma_f32_32x32x16_bf16(pa.v, vf1[1], o1, 0, 0, 0);
        __builtin_amdgcn_s_setprio(0);
    }
    {
        unsigned c0 = cvtpk(s1[0], s1[1]),  c1 = cvtpk(s1[2], s1[3]);
        unsigned d0 = cvtpk(s1[4], s1[5]),  d1 = cvtpk(s1[6], s1[7]);
        plswap(c0, d0); plswap(c1, d1);
        union { i32x4 i; bf16x8 v; } pa;
        pa.i[0] = (int)c0; pa.i[1] = (int)c1; pa.i[2] = (int)d0; pa.i[3] = (int)d1;
        __builtin_amdgcn_s_setprio(1);
        o0 = __builtin_amdgcn_mfma_f32_32x32x16_bf16(pa.v, vf0[2], o0, 0, 0, 0);
        o1 = __builtin_amdgcn_mfma_f32_32x32x16_bf16(pa.v, vf1[2], o1, 0, 0, 0);
        __builtin_amdgcn_s_setprio(0);
    }
    {
        unsigned c0 = cvtpk(s1[8], s1[9]),   c1 = cvtpk(s1[10], s1[11]);
        unsigned d0 = cvtpk(s1[12], s1[13]), d1 = cvtpk(s1[14], s1[15]);
        plswap(c0, d0); plswap(c1, d1);
        union { i32x4 i; bf16x8 v; } pa;
        pa.i[0] = (int)c0; pa.i[1] = (int)c1; pa.i[2] = (int)d0; pa.i[3] = (int)d1;
        __builtin_amdgcn_s_setprio(1);
        o0 = __builtin_amdgcn_mfma_f32_32x32x16_bf16(pa.v, vf0[3], o0, 0, 0, 0);
        o1 = __builtin_amdgcn_mfma_f32_32x32x16_bf16(pa.v, vf1[3], o1, 0, 0, 0);
        __builtin_amdgcn_s_setprio(0);
    }
}

// 1 wave = 32 q-rows, 4 independent waves/block, grid (32, B*H). No LDS, no barriers.
__global__ __launch_bounds__(256, 2) void attn(const ushort* __restrict__ Q, const ushort* __restrict__ Kg,
                                               const ushort* __restrict__ VT, ushort* __restrict__ AO) {
    const int tid = threadIdx.x;
    const int lane = tid & 63;
    const int wid = tid >> 6;
    const int l31 = lane & 31;
    const int hi  = lane >> 5;
    const int bh = blockIdx.y;
    const int b = bh >> 3, h = bh & 7;
    const int q0 = blockIdx.x * 128 + wid * 32;
    const size_t base = (size_t)bh * (4096 * 64);

    const float qscale = 0.125f * 1.44269504088896f;   // exp2-domain softmax
    bf16x8 qf[4];
    {
        const ushort* qp = Q + base + (size_t)(q0 + l31) * 64 + hi * 8;
#pragma unroll
        for (int ks = 0; ks < 4; ++ks) {
            bf16x8 t = *(const bf16x8*)(qp + ks * 16);
#pragma unroll
            for (int e = 0; e < 8; ++e) t[e] = (short)f2bf(bf2f((ushort)t[e]) * qscale);
            qf[ks] = t;
        }
    }
    f32x16 o0 = zero16(), o1 = zero16();
    float m_i = -1e30f, l_i = 0.f;

    const ushort* kbase = Kg + base + (size_t)l31 * 64 + hi * 8;
    const ushort* vb0 = VT + base + (size_t)l31 * 4096 + hi * 8;          // d-block 0
    const ushort* vb1 = VT + base + (size_t)(l31 + 32) * 4096 + hi * 8;   // d-block 1

    bf16x8 kA[8], kB[8];
#pragma unroll
    for (int ks = 0; ks < 4; ++ks) {
        kA[ks]     = *(const bf16x8*)(kbase + (size_t)0 + ks * 16);
        kA[ks + 4] = *(const bf16x8*)(kbase + (size_t)32 * 64 + ks * 16);
    }
    for (int kt2 = 0; kt2 < 32; ++kt2) {
        attn_step(kbase, vb0, vb1, qf, kA, kB, o0, o1, m_i, l_i, kt2 * 2);
        attn_step(kbase, vb0, vb1, qf, kB, kA, o0, o1, m_i, l_i, kt2 * 2 + 1);
    }
    // ---- epilogue
    float linv = 1.0f / l_i;
#pragma unroll
    for (int r = 0; r < 16; ++r) {
        int q = (r & 3) + 8 * (r >> 2) + 4 * hi;
        float so = __shfl(linv, q);
        int n = q0 + q;
        ushort* op = AO + ((size_t)(b * 4096 + n)) * 512 + h * 64 + l31;
        op[0]  = f2bf(o0[r] * so);
        op[32] = f2bf(o1[r] * so);
    }
}

// ---------------- GEMM: out = AO[8192][512] @ lin_w[512][512] + b  (fp32 out) ----------------
__global__ __launch_bounds__(256) void gemm_out(const ushort* __restrict__ A, const ushort* __restrict__ Wt,
                                                const float* __restrict__ bias, float* __restrict__ out) {
    __shared__ __align__(16) ushort As[128 * 64];
    __shared__ __align__(16) ushort Bs[128 * 64];
    const int tid = threadIdx.x;
    const int lane = tid & 63;
    const int wid = tid >> 6;
    const int m0 = blockIdx.x * 128;
    const int n0 = blockIdx.y * 128;
    const int wm = (wid >> 1) * 64;
    const int wn = (wid & 1) * 64;
    const int g = lane >> 4;
    const int r16 = lane & 15;
    const int srow = tid >> 3;
    const int scol = (tid & 7) * 8;
    f32x4 acc[4][4] = {};
    for (int k0 = 0; k0 < 512; k0 += 64) {
#pragma unroll
        for (int c = 0; c < 4; ++c) {
            int row = srow + c * 32;
            gload_lds16(A  + (size_t)(m0 + row) * 512 + k0 + scol, As + row * 64 + scol);
            gload_lds16(Wt + (size_t)(n0 + row) * 512 + k0 + scol, Bs + row * 64 + scol);
        }
        asm volatile("s_waitcnt vmcnt(0)" ::: "memory");
        __syncthreads();
#pragma unroll
        for (int kk = 0; kk < 2; ++kk) {
            bf16x8 af[4], bfr[4];
#pragma unroll
            for (int t = 0; t < 4; ++t) af[t]  = *(const bf16x8*)(As + (wm + t * 16 + r16) * 64 + kk * 32 + g * 8);
#pragma unroll
            for (int t = 0; t < 4; ++t) bfr[t] = *(const bf16x8*)(Bs + (wn + t * 16 + r16) * 64 + kk * 32 + g * 8);
#pragma unroll
            for (int mt = 0; mt < 4; ++mt)
#pragma unroll
                for (int nt = 0; nt < 4; ++nt)
                    acc[mt][nt] = __builtin_amdgcn_mfma_f32_16x16x32_bf16(af[mt], bfr[nt], acc[mt][nt], 0, 0, 0);
        }
        __syncthreads();
    }
    const int rbase = g * 4;
#pragma unroll
    for (int nt = 0; nt < 4; ++nt) {
        int col = n0 + wn + nt * 16 + r16;
        float bv = bias[col];
#pragma unroll
        for (int mt = 0; mt < 4; ++mt) {
#pragma unroll
            for (int r = 0; r < 4; ++r) {
                int rowm = m0 + wm + mt * 16 + rbase + r;
                out[(size_t)rowm * 512 + col] = acc[mt][nt][r] + bv;
            }
        }
    }
}

extern "C" void kernel_launch(void* const* d_in, const int* in_sizes, int n_in,
                              void* d_out, int out_size, void* d_ws, size_t ws_size,
                              hipStream_t stream) {
    const float* x     = (const float*)d_in[0];
    const float* qkv_w = (const float*)d_in[1];
    const float* lin_w = (const float*)d_in[2];
    const float* lin_b = (const float*)d_in[3];
    float* out = (float*)d_out;
    char* ws = (char*)d_ws;
    ushort* xb    = (ushort*)(ws + 0);                       // 8 MB
    ushort* qkvwt = (ushort*)(ws + 8388608);                 // 1.5 MB
    ushort* linwt = (ushort*)(ws + 8388608 + 1572864);       // 0.5 MB
    ushort* Qb    = (ushort*)(ws + 10485760);                // 8 MB
    ushort* Kb    = (ushort*)(ws + 10485760 + 8388608);      // 8 MB
    ushort* VTb   = (ushort*)(ws + 10485760 + 16777216);     // 8 MB
    ushort* AOb   = (ushort*)(ws + 10485760 + 25165824);     // 8 MB (end = 44,040,192)

    prep_x<<<4096, 256, 0, stream>>>(x, xb);
    transpose_w<<<dim3(8, 24), 256, 0, stream>>>(qkv_w, qkvwt, 512, 1536);
    transpose_w<<<dim3(8, 8), 256, 0, stream>>>(lin_w, linwt, 512, 512);
    gemm_qkv<<<dim3(64, 12), 256, 0, stream>>>(xb, qkvwt, Qb, Kb, VTb);
    attn<<<dim3(32, 16), 256, 0, stream>>>(Qb, Kb, VTb, AOb);
    gemm_out<<<dim3(64, 4), 256, 0, stream>>>(AOb, linwt, lin_b, out);
}